// Round 17
// baseline (169.149 us; speedup 1.0000x reference)
//
#include <hip/hip_runtime.h>
#include <math.h>

#define M_PIf 3.14159265358979323846f
#define MIND (-3.0701134573253936f)
#define MAXD (-15.350567286626968f)

typedef __attribute__((ext_vector_type(8))) _Float16 f16x8;
typedef __attribute__((ext_vector_type(4))) float f32x4;
typedef __attribute__((ext_vector_type(8))) unsigned short u16x8;

#define GLDS(g, l) __builtin_amdgcn_global_load_lds(                         \
    (const __attribute__((address_space(1))) void*)(g),                      \
    (__attribute__((address_space(3))) void*)(l), 16, 0, 0)

__device__ __forceinline__ unsigned short f2h(float x) {
    return __builtin_bit_cast(unsigned short, (_Float16)x);
}
__device__ __forceinline__ float h2f(unsigned short h) {
    return (float)__builtin_bit_cast(_Float16, h);
}

// ---------------------------------------------------------------------------
// prep_kernel: fused {split u->uh | tsplit in_w->w1t | filter MLP |
//                     tsplit out_w->w2t}
// ---------------------------------------------------------------------------
__global__ __launch_bounds__(256) void prep_kernel(
    const float* __restrict__ u, unsigned short* __restrict__ uh,
    const float* __restrict__ in_w, unsigned short* __restrict__ w1t,
    const float* __restrict__ w1, const float* __restrict__ b1,
    const float* __restrict__ w2, const float* __restrict__ b2,
    const float* __restrict__ w3, const float* __restrict__ b3,
    const float* __restrict__ wo, const float* __restrict__ freq,
    unsigned short* __restrict__ kbuf,
    const float* __restrict__ out_w, unsigned short* __restrict__ w2t)
{
    __shared__ char sm[4352];
    const int bid = blockIdx.x;
    const int tid = threadIdx.x;

    if (bid < 2048) {
#pragma unroll
        for (int q = 0; q < 4; ++q) {
            const int i = bid * 1024 + q * 256 + tid;
            float4 v = ((const float4*)u)[i];
            ushort4 h;
            h.x = f2h(v.x); h.y = f2h(v.y); h.z = f2h(v.z); h.w = f2h(v.w);
            ((ushort4*)uh)[i] = h;
        }
    } else if (bid < 5120) {
        float (*t)[33] = (float(*)[33])sm;
        const int idx = bid - 2048;
        const int bx = idx % 96, by = idx / 96;
        const int r0 = by * 32, c0 = bx * 32;
        const int tx = tid & 31, ty = tid >> 5;
#pragma unroll
        for (int q = 0; q < 4; ++q) {
            int r = ty + q * 8;
            t[r][tx] = in_w[(size_t)(r0 + r) * 3072 + c0 + tx];
        }
        __syncthreads();
#pragma unroll
        for (int q = 0; q < 4; ++q) {
            int cc = ty + q * 8;
            w1t[(size_t)(c0 + cc) * 1024 + r0 + tx] = f2h(t[tx][cc]);
        }
    } else if (bid < 5376) {
        float (*ha)[65] = (float(*)[65])sm;
        float (*hb)[65] = (float(*)[65])(sm + 2080);
        const int l0 = (bid - 5120) * 8;
        const int uu = tid & 63, lq = tid >> 6;
#pragma unroll
        for (int p = 0; p < 2; ++p) {
            int ll = lq + p * 4;
            int l = l0 + ll;
            float t = (float)l * (1.0f / 2047.0f);
            float ang = 1e-4f * (2.0f * M_PIf) * ((float)l / 2048.0f);
            float pre = t * w1[uu] + cosf(ang) * w1[64 + uu] - sinf(ang) * w1[128 + uu] + b1[uu];
            ha[ll][uu] = sinf(freq[uu] * pre);
        }
        __syncthreads();
#pragma unroll
        for (int p = 0; p < 2; ++p) {
            int ll = lq + p * 4;
            float s = b2[uu];
#pragma unroll
            for (int i = 0; i < 64; ++i) s += ha[ll][i] * w2[i * 64 + uu];
            hb[ll][uu] = sinf(freq[uu] * s);
        }
        __syncthreads();
#pragma unroll
        for (int p = 0; p < 2; ++p) {
            int ll = lq + p * 4;
            float s = b3[uu];
#pragma unroll
            for (int i = 0; i < 64; ++i) s += hb[ll][i] * w3[i * 64 + uu];
            ha[ll][uu] = sinf(freq[uu] * s);
        }
        __syncthreads();

        float acc[4][8] = {};
        for (int i = 0; i < 64; ++i) {
            float wv[4];
#pragma unroll
            for (int q = 0; q < 4; ++q) wv[q] = wo[i * 1024 + tid + 256 * q];
#pragma unroll
            for (int l = 0; l < 8; ++l) {
                float hv = ha[l][i];
#pragma unroll
                for (int q = 0; q < 4; ++q) acc[q][l] += hv * wv[q];
            }
        }
        const float span = (MAXD - MIND) * (1.0f / 1023.0f);
#pragma unroll
        for (int q = 0; q < 4; ++q) {
            int dd = tid + 256 * q;
            float ad = fabsf(MIND + span * (float)dd);
#pragma unroll
            for (int l = 0; l < 8; ++l) {
                float t = (float)(l0 + l) * (1.0f / 2047.0f);
                kbuf[(size_t)dd * 2048 + l0 + l] = f2h(acc[q][l] * expf(-t * ad));
            }
        }
    } else {
        float (*t)[33] = (float(*)[33])sm;
        const int idx = bid - 5376;
        const int bx = idx & 31, by = idx >> 5;
        const int r0 = by * 32, c0 = bx * 32;
        const int tx = tid & 31, ty = tid >> 5;
#pragma unroll
        for (int q = 0; q < 4; ++q) {
            int r = ty + q * 8;
            t[r][tx] = out_w[(size_t)(r0 + r) * 1024 + c0 + tx];
        }
        __syncthreads();
#pragma unroll
        for (int q = 0; q < 4; ++q) {
            int cc = ty + q * 8;
            w2t[(size_t)(c0 + cc) * 1024 + r0 + tx] = f2h(t[tx][cc]);
        }
    }
}

// ---------------------------------------------------------------------------
// post_kernel: t16 yvh[b][d][l] -> yvt[b][l][d], 64x64 tiles (2048 blocks)
// ---------------------------------------------------------------------------
__global__ __launch_bounds__(256) void post_kernel(
    const unsigned short* __restrict__ yvh, unsigned short* __restrict__ yvt)
{
    __shared__ unsigned short t[64][66];
    const int bid = blockIdx.x;
    const int tid = threadIdx.x;
    const int l0 = (bid & 31) * 64;
    const int d0 = ((bid >> 5) & 15) * 64;
    const int b  = bid >> 9;
    const int rr = tid >> 4, cc = (tid & 15) * 4;
#pragma unroll
    for (int p = 0; p < 4; ++p) {
        int r = p * 16 + rr;
        ushort4 v = *(const ushort4*)&yvh[((size_t)b * 1024 + d0 + r) * 2048 + l0 + cc];
        t[cc + 0][r] = v.x; t[cc + 1][r] = v.y; t[cc + 2][r] = v.z; t[cc + 3][r] = v.w;
    }
    __syncthreads();
#pragma unroll
    for (int p = 0; p < 4; ++p) {
        int r = p * 16 + rr;
        ushort4 o;
        o.x = t[r][cc + 0]; o.y = t[r][cc + 1]; o.z = t[r][cc + 2]; o.w = t[r][cc + 3];
        *(ushort4*)&yvt[((size_t)b * 2048 + l0 + r) * 1024 + d0 + cc] = o;
    }
}

// ---------------------------------------------------------------------------
// 8-phase fp16 MFMA GEMM (round-14/16 best: 8-phase + T1 + T2 swizzle).
// BM=256, BN=128, BK=64. 512 threads = 8 waves (4m x 2n), per-wave 64x64.
// vmcnt(3) at ph4/ph8 (vmcnt(0) last iter). Bank conflicts = 0 (verified).
// ---------------------------------------------------------------------------
template <int TRANS_OUT>
__global__ __launch_bounds__(512, 1) void gemm8_f16_kernel(
    const unsigned short* __restrict__ A, const unsigned short* __restrict__ B,
    const float* __restrict__ bias, void* __restrict__ outp)
{
    __shared__ char smem[98304];   // bufA @0, bufB @49152
    const int tid = threadIdx.x;
    const int wave = tid >> 6, lane = tid & 63;
    const int nwg = gridDim.x * gridDim.y;
    const int lin = blockIdx.y * gridDim.x + blockIdx.x;
    const int wid = (lin & 7) * (nwg >> 3) + (lin >> 3);
    const int n0 = (wid % gridDim.x) * 128;
    const int m0 = (wid / gridDim.x) * 256;
    const int wm = wave >> 1, wn = wave & 1;
    const int rr = lane & 15, g4 = lane >> 4;
    const int srow4 = lane >> 2;
    const int sswz  = ((lane & 3) ^ ((lane >> 3) & 3)) * 8;
    const int axor  = (g4 ^ ((rr >> 1) & 3)) * 16;

    f32x4 acc[4][4] = {};
    f16x8 bq[4];

    auto stageA = [&](int bufo, int t, int kh) {
        const int ke = t * 64 + kh * 32;
        char* ldsb = smem + bufo + kh * 16384 + wave * 1024;
#pragma unroll
        for (int j = 0; j < 2; ++j) {
            const int rg = j * 128 + wave * 16 + srow4;
            GLDS((const char*)(A + (size_t)(m0 + rg) * 1024 + ke + sswz), ldsb + j * 8192);
        }
    };
    auto stageB = [&](int bufo, int t, int kh) {
        const int ke = t * 64 + kh * 32;
        const int rg = wave * 16 + srow4;
        GLDS((const char*)(B + (size_t)(n0 + rg) * 1024 + ke + sswz),
             smem + bufo + 32768 + kh * 8192 + wave * 1024);
    };

    auto phase = [&](int bufo, int s, int h, auto stage_fn, int vm) {
        const char* bb = smem + bufo;
        f16x8 aq0, aq1;
        if (h == 0) {
#pragma unroll
            for (int j = 0; j < 4; ++j)
                bq[j] = *(const f16x8*)(bb + 32768 + s * 8192 + (wn * 64 + j * 16 + rr) * 64 + axor);
        }
        aq0 = *(const f16x8*)(bb + s * 16384 + (wm * 64 + (h * 2 + 0) * 16 + rr) * 64 + axor);
        aq1 = *(const f16x8*)(bb + s * 16384 + (wm * 64 + (h * 2 + 1) * 16 + rr) * 64 + axor);
        stage_fn();
        __builtin_amdgcn_s_barrier();
        __builtin_amdgcn_s_setprio(1);
#pragma unroll
        for (int j = 0; j < 4; ++j)
            acc[h * 2 + 0][j] = __builtin_amdgcn_mfma_f32_16x16x32_f16(aq0, bq[j], acc[h * 2 + 0][j], 0, 0, 0);
#pragma unroll
        for (int j = 0; j < 4; ++j)
            acc[h * 2 + 1][j] = __builtin_amdgcn_mfma_f32_16x16x32_f16(aq1, bq[j], acc[h * 2 + 1][j], 0, 0, 0);
        __builtin_amdgcn_s_setprio(0);
        if (vm == 1) asm volatile("s_waitcnt vmcnt(3)" ::: "memory");
        else if (vm == 2) asm volatile("s_waitcnt vmcnt(0)" ::: "memory");
        __builtin_amdgcn_s_barrier();
    };

    // prologue: T0 full + T1.kh0
    stageA(0, 0, 0); stageB(0, 0, 0);
    stageA(0, 0, 1); stageB(0, 0, 1);
    stageA(49152, 1, 0); stageB(49152, 1, 0);
    asm volatile("s_waitcnt vmcnt(0)" ::: "memory");
    __syncthreads();

    for (int it = 0; it < 8; ++it) {
        const int T1 = 2 * it + 1, T2 = 2 * it + 2, T3 = 2 * it + 3;
        const int vmL = (it == 7) ? 2 : 1;
        phase(0,     0, 0, [&] { stageA(49152, T1, 1); }, 0);
        phase(0,     0, 1, [&] { stageB(49152, T1, 1); }, 0);
        phase(0,     1, 0, [&] { if (T2 < 16) stageA(0, T2, 0); }, 0);
        phase(0,     1, 1, [&] { if (T2 < 16) stageB(0, T2, 0); }, vmL);
        phase(49152, 0, 0, [&] { if (T2 < 16) stageA(0, T2, 1); }, 0);
        phase(49152, 0, 1, [&] { if (T2 < 16) stageB(0, T2, 1); }, 0);
        phase(49152, 1, 0, [&] { if (T3 < 16) stageA(49152, T3, 0); }, 0);
        phase(49152, 1, 1, [&] { if (T3 < 16) stageB(49152, T3, 0); }, vmL);
    }

    const int c = rr;
    if (TRANS_OUT) {
        unsigned short* up = (unsigned short*)outp;
        const int bidx = m0 >> 11;
        const int lbase = (m0 & 2047) + wm * 64 + g4 * 4;
#pragma unroll
        for (int j = 0; j < 4; ++j) {
            const int e = n0 + wn * 64 + j * 16 + c;
            const float bv = bias[e];
            unsigned short* dst = up + ((size_t)bidx * 3072 + e) * 2048 + lbase;
#pragma unroll
            for (int i = 0; i < 4; ++i) {
                ushort4 o;
                o.x = f2h(acc[i][j][0] + bv);
                o.y = f2h(acc[i][j][1] + bv);
                o.z = f2h(acc[i][j][2] + bv);
                o.w = f2h(acc[i][j][3] + bv);
                *(ushort4*)(dst + i * 16) = o;
            }
        }
    } else {
        float* op = (float*)outp;
#pragma unroll
        for (int j = 0; j < 4; ++j) {
            const int col = n0 + wn * 64 + j * 16 + c;
            const float bv = bias[col];
#pragma unroll
            for (int i = 0; i < 4; ++i) {
                const int row = m0 + wm * 64 + i * 16 + g4 * 4;
#pragma unroll
                for (int r = 0; r < 4; ++r)
                    op[(size_t)(row + r) * 1024 + col] = acc[i][j][r] + bv;
            }
        }
    }
}

// ---------------------------------------------------------------------------
// conv3 on one aligned 8-chunk of an fp16 row, from 2 vector loads.
// NOTE: main load MUST be f16x8 (half->float), not u16x8 (round-7 NaN bug).
// ---------------------------------------------------------------------------
__device__ __forceinline__ void conv3_chunk(
    const unsigned short* __restrict__ row, int l0,
    float wa, float wb, float wc, float sbv, float out[8])
{
    f16x8 m = *(const f16x8*)(row + l0);
    float e[10];
    if (l0 > 0) {
        ushort2 p = *(const ushort2*)(row + l0 - 2);
        e[0] = h2f(p.x); e[1] = h2f(p.y);
    } else {
        e[0] = 0.f; e[1] = 0.f;
    }
#pragma unroll
    for (int i = 0; i < 8; ++i) e[2 + i] = (float)m[i];
#pragma unroll
    for (int i = 0; i < 8; ++i)
        out[i] = wa * e[i] + wb * e[i + 1] + wc * e[i + 2] + sbv;
}

// ---------------------------------------------------------------------------
// MFMA Toeplitz causal conv (fp16 in/out), fused depthwise conv3 gating.
// wpk4 OPTIMIZATION: the sweep's A-fragment used to be 4 scalar ds_read_b32
// (stride-2 dwords, ~47 cyc/step LDS-pipe vs 41 MFMA -> LDS-bound). Now the
// window array is pre-expanded to wpk4[x] = {wpk[x],wpk[x+2],wpk[x+4],
// wpk[x+6]} (int4, 16B-aligned) -> one ds_read_b128 per step (~36 cyc/step).
// Wave address pattern (16 lanes x descending 16B) is contiguous ->
// conflict-free. Temp wpk overlays x0's region (dead before x0 written).
// LDS 52.5KB -> 3 blocks/CU. DETERMINISM: all global reads in-bounds.
// ---------------------------------------------------------------------------
__global__ __launch_bounds__(256, 3) void conv_kernel(
    const unsigned short* __restrict__ up_t, const unsigned short* __restrict__ kbuf,
    const float* __restrict__ sw, const float* __restrict__ sb,
    const float* __restrict__ fbias, unsigned short* __restrict__ yv)
{
    __shared__ char smem[52480];
    // vx per bb: ushort[2304] @ bb*4608            [0, 9216)
    // wpk4: int4[2064] @ 9216                      [9216, 42240)
    // x0 per bb: ushort[2560] @ 42240 + bb*5120    [42240, 52480)
    // temp wpk: int[2070] @ 42240 (dead before x0 writes)
#define VH(bb) ((unsigned short*)(smem + (bb) * 4608))
#define X0(bb) ((unsigned short*)(smem + 42240 + (bb) * 5120))
    int4* wpk4 = (int4*)(smem + 9216);
    int*  wtmp = (int*)(smem + 42240);

    const int d = blockIdx.x;
    const int bqa = blockIdx.y * 2;
    const int tid = threadIdx.x;

    // ---- phase 0a-1: reversed-k pair-dword temp array ----------------------
    const unsigned short* kr = kbuf + (size_t)d * 2048;
    for (int xc = tid * 4; xc < 2064; xc += 1024) {
        int4 w4 = {0, 0, 0, 0};
        if (xc <= 2044) {
            const ushort4 fv = *(const ushort4*)&kr[2044 - xc];
            const unsigned e = (xc <= 2040) ? (unsigned)kr[2043 - xc] : 0u;
            w4.x = (int)((unsigned)fv.w | ((unsigned)fv.z << 16));
            w4.y = (int)((unsigned)fv.z | ((unsigned)fv.y << 16));
            w4.z = (int)((unsigned)fv.y | ((unsigned)fv.x << 16));
            w4.w = (int)((unsigned)fv.x | (e << 16));
        }
        *(int4*)&wtmp[xc] = w4;
    }
    if (tid < 6) wtmp[2064 + tid] = 0;
    __syncthreads();
    // ---- phase 0a-2: expand to wpk4 (one b128 per sweep step later) --------
    for (int x = tid; x < 2064; x += 256) {
        int4 e;
        e.x = wtmp[x];     e.y = wtmp[x + 2];
        e.z = wtmp[x + 4]; e.w = wtmp[x + 6];
        wpk4[x] = e;
    }
    __syncthreads();

    // ---- phase 0b: vectorized conv3 staging (x0 overwrites wtmp - safe) ----
    const float w1a = sw[(1024 + d) * 3 + 0], w1b = sw[(1024 + d) * 3 + 1], w1c = sw[(1024 + d) * 3 + 2];
    const float w2a = sw[(2048 + d) * 3 + 0], w2b = sw[(2048 + d) * 3 + 1], w2c = sw[(2048 + d) * 3 + 2];
    const float w0a = sw[d * 3 + 0], w0b = sw[d * 3 + 1], w0c = sw[d * 3 + 2];
    const float sb1 = sb[1024 + d], sb2 = sb[2048 + d], sb0 = sb[d];
    const int l0 = tid * 8;
#pragma unroll
    for (int bb = 0; bb < 2; ++bb) {
        const int b = bqa + bb;
        const unsigned short* rx1 = up_t + ((size_t)(b * 3072) + 1024 + d) * 2048;
        const unsigned short* rv  = up_t + ((size_t)(b * 3072) + 2048 + d) * 2048;
        const unsigned short* r0  = up_t + ((size_t)(b * 3072) + d) * 2048;
        float x1v[8], vv[8], x0v[8];
        conv3_chunk(rx1, l0, w1a, w1b, w1c, sb1, x1v);
        conv3_chunk(rv,  l0, w2a, w2b, w2c, sb2, vv);
        conv3_chunk(r0,  l0, w0a, w0b, w0c, sb0, x0v);
        u16x8 o;
#pragma unroll
        for (int i = 0; i < 8; ++i) o[i] = f2h(vv[i] * x1v[i]);
        *(u16x8*)(VH(bb) + 240 + l0) = o;
        const int xo = l0 + 4 * (l0 >> 4);
        ushort4 p1, p2;
        p1.x = f2h(x0v[0]); p1.y = f2h(x0v[1]); p1.z = f2h(x0v[2]); p1.w = f2h(x0v[3]);
        p2.x = f2h(x0v[4]); p2.y = f2h(x0v[5]); p2.z = f2h(x0v[6]); p2.w = f2h(x0v[7]);
        *(ushort4*)(X0(bb) + xo) = p1;
        *(ushort4*)(X0(bb) + xo + 4) = p2;
        if (tid < 30) {
            u16x8 z = {};
            *(u16x8*)(VH(bb) + tid * 8) = z;
        }
    }
    __syncthreads();

    // ---- phase 1: MFMA Toeplitz sweep (1 b128 A-read per step) -------------
    const int wv = tid >> 6, lane = tid & 63;
    const int row = lane & 15;
    const int sseg = lane >> 4;
    f32x4 acc[2][2] = {};
#pragma unroll
    for (int gi = 0; gi < 2; ++gi) {
        const int g = gi ? (7 - wv) : wv;
        const int tmax = 8 * g + 8;
        int xA = 2031 - row + 8 * sseg;
        int xB = 224 + 256 * g + 16 * row + 8 * sseg;
        auto step = [&]() {
            f16x8 ah = __builtin_bit_cast(f16x8, wpk4[xA]);
#pragma unroll
            for (int bb = 0; bb < 2; ++bb) {
                f16x8 bh = *(const f16x8*)(VH(bb) + xB);
                acc[gi][bb] = __builtin_amdgcn_mfma_f32_16x16x32_f16(ah, bh, acc[gi][bb], 0, 0, 0);
            }
            xA -= 32;
            xB -= 32;
        };
        for (int t = 0; t < tmax; t += 2) { step(); step(); }
    }

    // ---- phase 2: epilogue, all from LDS -----------------------------------
    const float fb = fbias[d];
#pragma unroll
    for (int gi = 0; gi < 2; ++gi) {
        const int g = gi ? (7 - wv) : wv;
        const int lb = 256 * g + 16 * row + 4 * sseg;
#pragma unroll
        for (int bb = 0; bb < 2; ++bb) {
            ushort4 vhq = *(const ushort4*)(VH(bb) + 240 + lb);
            ushort4 x0q = *(const ushort4*)(X0(bb) + lb + 4 * (lb >> 4));
            f32x4 a = acc[gi][bb];
            ushort4 o;
            o.x = f2h((a[0] + h2f(vhq.x) * fb) * h2f(x0q.x));
            o.y = f2h((a[1] + h2f(vhq.y) * fb) * h2f(x0q.y));
            o.z = f2h((a[2] + h2f(vhq.z) * fb) * h2f(x0q.z));
            o.w = f2h((a[3] + h2f(vhq.w) * fb) * h2f(x0q.w));
            *(ushort4*)&yv[((size_t)((bqa + bb) * 1024) + d) * 2048 + lb] = o;
        }
    }
#undef VH
#undef X0
}

extern "C" void kernel_launch(void* const* d_in, const int* in_sizes, int n_in,
                              void* d_out, int out_size, void* d_ws, size_t ws_size,
                              hipStream_t stream) {
    (void)in_sizes; (void)n_in; (void)out_size; (void)ws_size;
    const float* u         = (const float*)d_in[0];
    const float* in_w      = (const float*)d_in[1];
    const float* in_b      = (const float*)d_in[2];
    const float* short_w   = (const float*)d_in[3];
    const float* short_b   = (const float*)d_in[4];
    const float* mlp_w1    = (const float*)d_in[5];
    const float* mlp_b1    = (const float*)d_in[6];
    const float* mlp_w2    = (const float*)d_in[7];
    const float* mlp_b2    = (const float*)d_in[8];
    const float* mlp_w3    = (const float*)d_in[9];
    const float* mlp_b3    = (const float*)d_in[10];
    const float* mlp_wo    = (const float*)d_in[11];
    const float* freq      = (const float*)d_in[12];
    const float* filt_bias = (const float*)d_in[13];
    const float* out_w     = (const float*)d_in[14];
    const float* out_b     = (const float*)d_in[15];
    float* out = (float*)d_out;

    char* ws = (char*)d_ws;
    const size_t MB = 1024 * 1024;
    unsigned short* up_t  = (unsigned short*)ws;              // [0,48M) fp16
    unsigned short* yvh   = (unsigned short*)(ws + 48 * MB);  // [48,64M) fp16 [b][d][l]
    unsigned short* yvt   = (unsigned short*)(ws + 64 * MB);  // [64,80M) fp16 [b][l][d]
    unsigned short* w2t   = (unsigned short*)(ws + 80 * MB);  // [80,82M)
    unsigned short* kbuf  = (unsigned short*)(ws + 82 * MB);  // [82,86M) fp16
    unsigned short* uh    = (unsigned short*)(ws + 90 * MB);  // [90,106M)
    unsigned short* w1t   = (unsigned short*)(ws + 106 * MB); // [106,112M)

    hipLaunchKernelGGL(prep_kernel, dim3(6400), dim3(256), 0, stream,
                       u, uh, in_w, w1t,
                       mlp_w1, mlp_b1, mlp_w2, mlp_b2, mlp_w3, mlp_b3, mlp_wo, freq, kbuf,
                       out_w, w2t);
    hipLaunchKernelGGL((gemm8_f16_kernel<1>), dim3(24, 32), dim3(512), 0, stream,
                       uh, w1t, in_b, (void*)up_t);
    hipLaunchKernelGGL(conv_kernel, dim3(1024, 2), dim3(256), 0, stream,
                       up_t, kbuf, short_w, short_b, filt_bias, yvh);
    hipLaunchKernelGGL(post_kernel, dim3(2048), dim3(256), 0, stream,
                       yvh, yvt);
    hipLaunchKernelGGL((gemm8_f16_kernel<0>), dim3(8, 32), dim3(512), 0, stream,
                       yvt, w2t, out_b, (void*)out);
}

// Round 18
// 164.673 us; speedup vs baseline: 1.0272x; 1.0272x over previous
//
#include <hip/hip_runtime.h>
#include <math.h>

#define M_PIf 3.14159265358979323846f
#define MIND (-3.0701134573253936f)
#define MAXD (-15.350567286626968f)

typedef __attribute__((ext_vector_type(8))) _Float16 f16x8;
typedef __attribute__((ext_vector_type(4))) float f32x4;
typedef __attribute__((ext_vector_type(8))) unsigned short u16x8;

#define GLDS(g, l) __builtin_amdgcn_global_load_lds(                         \
    (const __attribute__((address_space(1))) void*)(g),                      \
    (__attribute__((address_space(3))) void*)(l), 16, 0, 0)

__device__ __forceinline__ unsigned short f2h(float x) {
    return __builtin_bit_cast(unsigned short, (_Float16)x);
}
__device__ __forceinline__ float h2f(unsigned short h) {
    return (float)__builtin_bit_cast(_Float16, h);
}

// ---------------------------------------------------------------------------
// prep_kernel: fused {split u->uh | tsplit in_w->w1t | filter MLP |
//                     tsplit out_w->w2t}
//   [0, 2048)      : split u (4 float4/thread)
//   [2048, 5120)   : tsplit in_w [1024][3072] -> w1t [3072][1024]
//   [5120, 5376)   : filt, l0 = (bid-5120)*8  (kbuf fp16)
//   [5376, 6400)   : tsplit out_w [1024][1024] -> w2t
// ---------------------------------------------------------------------------
__global__ __launch_bounds__(256) void prep_kernel(
    const float* __restrict__ u, unsigned short* __restrict__ uh,
    const float* __restrict__ in_w, unsigned short* __restrict__ w1t,
    const float* __restrict__ w1, const float* __restrict__ b1,
    const float* __restrict__ w2, const float* __restrict__ b2,
    const float* __restrict__ w3, const float* __restrict__ b3,
    const float* __restrict__ wo, const float* __restrict__ freq,
    unsigned short* __restrict__ kbuf,
    const float* __restrict__ out_w, unsigned short* __restrict__ w2t)
{
    __shared__ char sm[4352];
    const int bid = blockIdx.x;
    const int tid = threadIdx.x;

    if (bid < 2048) {
#pragma unroll
        for (int q = 0; q < 4; ++q) {
            const int i = bid * 1024 + q * 256 + tid;
            float4 v = ((const float4*)u)[i];
            ushort4 h;
            h.x = f2h(v.x); h.y = f2h(v.y); h.z = f2h(v.z); h.w = f2h(v.w);
            ((ushort4*)uh)[i] = h;
        }
    } else if (bid < 5120) {
        float (*t)[33] = (float(*)[33])sm;
        const int idx = bid - 2048;
        const int bx = idx % 96, by = idx / 96;
        const int r0 = by * 32, c0 = bx * 32;
        const int tx = tid & 31, ty = tid >> 5;
#pragma unroll
        for (int q = 0; q < 4; ++q) {
            int r = ty + q * 8;
            t[r][tx] = in_w[(size_t)(r0 + r) * 3072 + c0 + tx];
        }
        __syncthreads();
#pragma unroll
        for (int q = 0; q < 4; ++q) {
            int cc = ty + q * 8;
            w1t[(size_t)(c0 + cc) * 1024 + r0 + tx] = f2h(t[tx][cc]);
        }
    } else if (bid < 5376) {
        float (*ha)[65] = (float(*)[65])sm;
        float (*hb)[65] = (float(*)[65])(sm + 2080);
        const int l0 = (bid - 5120) * 8;
        const int uu = tid & 63, lq = tid >> 6;
#pragma unroll
        for (int p = 0; p < 2; ++p) {
            int ll = lq + p * 4;
            int l = l0 + ll;
            float t = (float)l * (1.0f / 2047.0f);
            float ang = 1e-4f * (2.0f * M_PIf) * ((float)l / 2048.0f);
            float pre = t * w1[uu] + cosf(ang) * w1[64 + uu] - sinf(ang) * w1[128 + uu] + b1[uu];
            ha[ll][uu] = sinf(freq[uu] * pre);
        }
        __syncthreads();
#pragma unroll
        for (int p = 0; p < 2; ++p) {
            int ll = lq + p * 4;
            float s = b2[uu];
#pragma unroll
            for (int i = 0; i < 64; ++i) s += ha[ll][i] * w2[i * 64 + uu];
            hb[ll][uu] = sinf(freq[uu] * s);
        }
        __syncthreads();
#pragma unroll
        for (int p = 0; p < 2; ++p) {
            int ll = lq + p * 4;
            float s = b3[uu];
#pragma unroll
            for (int i = 0; i < 64; ++i) s += hb[ll][i] * w3[i * 64 + uu];
            ha[ll][uu] = sinf(freq[uu] * s);
        }
        __syncthreads();

        float acc[4][8] = {};
        for (int i = 0; i < 64; ++i) {
            float wv[4];
#pragma unroll
            for (int q = 0; q < 4; ++q) wv[q] = wo[i * 1024 + tid + 256 * q];
#pragma unroll
            for (int l = 0; l < 8; ++l) {
                float hv = ha[l][i];
#pragma unroll
                for (int q = 0; q < 4; ++q) acc[q][l] += hv * wv[q];
            }
        }
        const float span = (MAXD - MIND) * (1.0f / 1023.0f);
#pragma unroll
        for (int q = 0; q < 4; ++q) {
            int dd = tid + 256 * q;
            float ad = fabsf(MIND + span * (float)dd);
#pragma unroll
            for (int l = 0; l < 8; ++l) {
                float t = (float)(l0 + l) * (1.0f / 2047.0f);
                kbuf[(size_t)dd * 2048 + l0 + l] = f2h(acc[q][l] * expf(-t * ad));
            }
        }
    } else {
        float (*t)[33] = (float(*)[33])sm;
        const int idx = bid - 5376;
        const int bx = idx & 31, by = idx >> 5;
        const int r0 = by * 32, c0 = bx * 32;
        const int tx = tid & 31, ty = tid >> 5;
#pragma unroll
        for (int q = 0; q < 4; ++q) {
            int r = ty + q * 8;
            t[r][tx] = out_w[(size_t)(r0 + r) * 1024 + c0 + tx];
        }
        __syncthreads();
#pragma unroll
        for (int q = 0; q < 4; ++q) {
            int cc = ty + q * 8;
            w2t[(size_t)(c0 + cc) * 1024 + r0 + tx] = f2h(t[tx][cc]);
        }
    }
}

// ---------------------------------------------------------------------------
// post_kernel: t16 yvh[b][d][l] -> yvt[b][l][d], 64x64 tiles (2048 blocks)
// ---------------------------------------------------------------------------
__global__ __launch_bounds__(256) void post_kernel(
    const unsigned short* __restrict__ yvh, unsigned short* __restrict__ yvt)
{
    __shared__ unsigned short t[64][66];
    const int bid = blockIdx.x;
    const int tid = threadIdx.x;
    const int l0 = (bid & 31) * 64;
    const int d0 = ((bid >> 5) & 15) * 64;
    const int b  = bid >> 9;
    const int rr = tid >> 4, cc = (tid & 15) * 4;
#pragma unroll
    for (int p = 0; p < 4; ++p) {
        int r = p * 16 + rr;
        ushort4 v = *(const ushort4*)&yvh[((size_t)b * 1024 + d0 + r) * 2048 + l0 + cc];
        t[cc + 0][r] = v.x; t[cc + 1][r] = v.y; t[cc + 2][r] = v.z; t[cc + 3][r] = v.w;
    }
    __syncthreads();
#pragma unroll
    for (int p = 0; p < 4; ++p) {
        int r = p * 16 + rr;
        ushort4 o;
        o.x = t[r][cc + 0]; o.y = t[r][cc + 1]; o.z = t[r][cc + 2]; o.w = t[r][cc + 3];
        *(ushort4*)&yvt[((size_t)b * 2048 + l0 + r) * 1024 + d0 + cc] = o;
    }
}

// ---------------------------------------------------------------------------
// 8-phase fp16 MFMA GEMM (best measured: 8-phase + T1 + T2 swizzle).
// BM=256, BN=128, BK=64. 512 threads = 8 waves (4m x 2n), per-wave 64x64.
// LDS 96KB: 2 K-tile bufs. vmcnt(3) at ph4/ph8 (vmcnt(0) last iter).
// T2 swizzle (PROVEN, 0 conflicts): src chunk (lane&3)^((lane>>3)&3),
// read chunk g4^((rr>>1)&3). Linear LDS dest (rule #21).
// T1: wid = (lin%8)*(nwg/8)+lin/8 (nwg%8==0 -> bijective).
// ---------------------------------------------------------------------------
template <int TRANS_OUT>
__global__ __launch_bounds__(512, 1) void gemm8_f16_kernel(
    const unsigned short* __restrict__ A, const unsigned short* __restrict__ B,
    const float* __restrict__ bias, void* __restrict__ outp)
{
    __shared__ char smem[98304];   // bufA @0, bufB @49152
    const int tid = threadIdx.x;
    const int wave = tid >> 6, lane = tid & 63;
    const int nwg = gridDim.x * gridDim.y;
    const int lin = blockIdx.y * gridDim.x + blockIdx.x;
    const int wid = (lin & 7) * (nwg >> 3) + (lin >> 3);
    const int n0 = (wid % gridDim.x) * 128;
    const int m0 = (wid / gridDim.x) * 256;
    const int wm = wave >> 1, wn = wave & 1;
    const int rr = lane & 15, g4 = lane >> 4;
    const int srow4 = lane >> 2;
    const int sswz  = ((lane & 3) ^ ((lane >> 3) & 3)) * 8;
    const int axor  = (g4 ^ ((rr >> 1) & 3)) * 16;

    f32x4 acc[4][4] = {};
    f16x8 bq[4];

    auto stageA = [&](int bufo, int t, int kh) {
        const int ke = t * 64 + kh * 32;
        char* ldsb = smem + bufo + kh * 16384 + wave * 1024;
#pragma unroll
        for (int j = 0; j < 2; ++j) {
            const int rg = j * 128 + wave * 16 + srow4;
            GLDS((const char*)(A + (size_t)(m0 + rg) * 1024 + ke + sswz), ldsb + j * 8192);
        }
    };
    auto stageB = [&](int bufo, int t, int kh) {
        const int ke = t * 64 + kh * 32;
        const int rg = wave * 16 + srow4;
        GLDS((const char*)(B + (size_t)(n0 + rg) * 1024 + ke + sswz),
             smem + bufo + 32768 + kh * 8192 + wave * 1024);
    };

    auto phase = [&](int bufo, int s, int h, auto stage_fn, int vm) {
        const char* bb = smem + bufo;
        f16x8 aq0, aq1;
        if (h == 0) {
#pragma unroll
            for (int j = 0; j < 4; ++j)
                bq[j] = *(const f16x8*)(bb + 32768 + s * 8192 + (wn * 64 + j * 16 + rr) * 64 + axor);
        }
        aq0 = *(const f16x8*)(bb + s * 16384 + (wm * 64 + (h * 2 + 0) * 16 + rr) * 64 + axor);
        aq1 = *(const f16x8*)(bb + s * 16384 + (wm * 64 + (h * 2 + 1) * 16 + rr) * 64 + axor);
        stage_fn();
        __builtin_amdgcn_s_barrier();
        __builtin_amdgcn_s_setprio(1);
#pragma unroll
        for (int j = 0; j < 4; ++j)
            acc[h * 2 + 0][j] = __builtin_amdgcn_mfma_f32_16x16x32_f16(aq0, bq[j], acc[h * 2 + 0][j], 0, 0, 0);
#pragma unroll
        for (int j = 0; j < 4; ++j)
            acc[h * 2 + 1][j] = __builtin_amdgcn_mfma_f32_16x16x32_f16(aq1, bq[j], acc[h * 2 + 1][j], 0, 0, 0);
        __builtin_amdgcn_s_setprio(0);
        if (vm == 1) asm volatile("s_waitcnt vmcnt(3)" ::: "memory");
        else if (vm == 2) asm volatile("s_waitcnt vmcnt(0)" ::: "memory");
        __builtin_amdgcn_s_barrier();
    };

    // prologue: T0 full + T1.kh0
    stageA(0, 0, 0); stageB(0, 0, 0);
    stageA(0, 0, 1); stageB(0, 0, 1);
    stageA(49152, 1, 0); stageB(49152, 1, 0);
    asm volatile("s_waitcnt vmcnt(0)" ::: "memory");
    __syncthreads();

    for (int it = 0; it < 8; ++it) {
        const int T1 = 2 * it + 1, T2 = 2 * it + 2, T3 = 2 * it + 3;
        const int vmL = (it == 7) ? 2 : 1;
        phase(0,     0, 0, [&] { stageA(49152, T1, 1); }, 0);
        phase(0,     0, 1, [&] { stageB(49152, T1, 1); }, 0);
        phase(0,     1, 0, [&] { if (T2 < 16) stageA(0, T2, 0); }, 0);
        phase(0,     1, 1, [&] { if (T2 < 16) stageB(0, T2, 0); }, vmL);
        phase(49152, 0, 0, [&] { if (T2 < 16) stageA(0, T2, 1); }, 0);
        phase(49152, 0, 1, [&] { if (T2 < 16) stageB(0, T2, 1); }, 0);
        phase(49152, 1, 0, [&] { if (T3 < 16) stageA(49152, T3, 0); }, 0);
        phase(49152, 1, 1, [&] { if (T3 < 16) stageB(49152, T3, 0); }, vmL);
    }

    const int c = rr;
    if (TRANS_OUT) {
        // lane holds 4 consecutive l for fixed e -> direct ushort4 stores
        unsigned short* up = (unsigned short*)outp;
        const int bidx = m0 >> 11;
        const int lbase = (m0 & 2047) + wm * 64 + g4 * 4;
#pragma unroll
        for (int j = 0; j < 4; ++j) {
            const int e = n0 + wn * 64 + j * 16 + c;
            const float bv = bias[e];
            unsigned short* dst = up + ((size_t)bidx * 3072 + e) * 2048 + lbase;
#pragma unroll
            for (int i = 0; i < 4; ++i) {
                ushort4 o;
                o.x = f2h(acc[i][j][0] + bv);
                o.y = f2h(acc[i][j][1] + bv);
                o.z = f2h(acc[i][j][2] + bv);
                o.w = f2h(acc[i][j][3] + bv);
                *(ushort4*)(dst + i * 16) = o;
            }
        }
    } else {
        float* op = (float*)outp;
#pragma unroll
        for (int j = 0; j < 4; ++j) {
            const int col = n0 + wn * 64 + j * 16 + c;
            const float bv = bias[col];
#pragma unroll
            for (int i = 0; i < 4; ++i) {
                const int row = m0 + wm * 64 + i * 16 + g4 * 4;
#pragma unroll
                for (int r = 0; r < 4; ++r)
                    op[(size_t)(row + r) * 1024 + col] = acc[i][j][r] + bv;
            }
        }
    }
}

// ---------------------------------------------------------------------------
// conv3 on one aligned 8-chunk of an fp16 row, from 2 vector loads.
// NOTE: main load MUST be f16x8 (half->float), not u16x8 (round-7 NaN bug).
// ---------------------------------------------------------------------------
__device__ __forceinline__ void conv3_chunk(
    const unsigned short* __restrict__ row, int l0,
    float wa, float wb, float wc, float sbv, float out[8])
{
    f16x8 m = *(const f16x8*)(row + l0);
    float e[10];
    if (l0 > 0) {
        ushort2 p = *(const ushort2*)(row + l0 - 2);
        e[0] = h2f(p.x); e[1] = h2f(p.y);
    } else {
        e[0] = 0.f; e[1] = 0.f;
    }
#pragma unroll
    for (int i = 0; i < 8; ++i) e[2 + i] = (float)m[i];
#pragma unroll
    for (int i = 0; i < 8; ++i)
        out[i] = wa * e[i] + wb * e[i + 1] + wc * e[i + 2] + sbv;
}

// ---------------------------------------------------------------------------
// MFMA Toeplitz causal conv (fp16 in/out), fused depthwise conv3 gating.
// kbuf fp16. 27.7KB LDS -> 4 blocks/CU (best measured config; the round-17
// wpk4 pre-expansion regressed via occupancy loss and was reverted).
// DETERMINISM: all global reads strictly in-bounds (round-5 lesson).
// ---------------------------------------------------------------------------
__global__ __launch_bounds__(256, 4) void conv_kernel(
    const unsigned short* __restrict__ up_t, const unsigned short* __restrict__ kbuf,
    const float* __restrict__ sw, const float* __restrict__ sb,
    const float* __restrict__ fbias, unsigned short* __restrict__ yv)
{
    __shared__ char smem[27712];
#define VH(bb) ((unsigned short*)(smem + (bb) * 4608))
#define X0(bb) ((unsigned short*)(smem + 17472 + (bb) * 5120))
    int* wpk = (int*)(smem + 9216);

    const int d = blockIdx.x;
    const int bqa = blockIdx.y * 2;
    const int tid = threadIdx.x;

    const unsigned short* kr = kbuf + (size_t)d * 2048;
    for (int xc = tid * 4; xc < 2064; xc += 1024) {
        int4 w4 = {0, 0, 0, 0};
        if (xc <= 2044) {
            const ushort4 fv = *(const ushort4*)&kr[2044 - xc];
            const unsigned e = (xc <= 2040) ? (unsigned)kr[2043 - xc] : 0u;
            w4.x = (int)((unsigned)fv.w | ((unsigned)fv.z << 16));
            w4.y = (int)((unsigned)fv.z | ((unsigned)fv.y << 16));
            w4.z = (int)((unsigned)fv.y | ((unsigned)fv.x << 16));
            w4.w = (int)((unsigned)fv.x | (e << 16));
        }
        *(int4*)&wpk[xc] = w4;
    }

    const float w1a = sw[(1024 + d) * 3 + 0], w1b = sw[(1024 + d) * 3 + 1], w1c = sw[(1024 + d) * 3 + 2];
    const float w2a = sw[(2048 + d) * 3 + 0], w2b = sw[(2048 + d) * 3 + 1], w2c = sw[(2048 + d) * 3 + 2];
    const float w0a = sw[d * 3 + 0], w0b = sw[d * 3 + 1], w0c = sw[d * 3 + 2];
    const float sb1 = sb[1024 + d], sb2 = sb[2048 + d], sb0 = sb[d];
    const int l0 = tid * 8;
#pragma unroll
    for (int bb = 0; bb < 2; ++bb) {
        const int b = bqa + bb;
        const unsigned short* rx1 = up_t + ((size_t)(b * 3072) + 1024 + d) * 2048;
        const unsigned short* rv  = up_t + ((size_t)(b * 3072) + 2048 + d) * 2048;
        const unsigned short* r0  = up_t + ((size_t)(b * 3072) + d) * 2048;
        float x1v[8], vv[8], x0v[8];
        conv3_chunk(rx1, l0, w1a, w1b, w1c, sb1, x1v);
        conv3_chunk(rv,  l0, w2a, w2b, w2c, sb2, vv);
        conv3_chunk(r0,  l0, w0a, w0b, w0c, sb0, x0v);
        u16x8 o;
#pragma unroll
        for (int i = 0; i < 8; ++i) o[i] = f2h(vv[i] * x1v[i]);
        *(u16x8*)(VH(bb) + 240 + l0) = o;
        const int xo = l0 + 4 * (l0 >> 4);
        ushort4 p1, p2;
        p1.x = f2h(x0v[0]); p1.y = f2h(x0v[1]); p1.z = f2h(x0v[2]); p1.w = f2h(x0v[3]);
        p2.x = f2h(x0v[4]); p2.y = f2h(x0v[5]); p2.z = f2h(x0v[6]); p2.w = f2h(x0v[7]);
        *(ushort4*)(X0(bb) + xo) = p1;
        *(ushort4*)(X0(bb) + xo + 4) = p2;
        if (tid < 30) {
            u16x8 z = {};
            *(u16x8*)(VH(bb) + tid * 8) = z;
        }
    }
    __syncthreads();

    const int wv = tid >> 6, lane = tid & 63;
    const int row = lane & 15;
    const int sseg = lane >> 4;
    f32x4 acc[2][2] = {};
#pragma unroll
    for (int gi = 0; gi < 2; ++gi) {
        const int g = gi ? (7 - wv) : wv;
        const int tmax = 8 * g + 8;
        int xA = 2031 - row + 8 * sseg;
        int xB = 224 + 256 * g + 16 * row + 8 * sseg;
        auto step = [&]() {
            int4 avh;
            avh.x = wpk[xA];     avh.y = wpk[xA + 2];
            avh.z = wpk[xA + 4]; avh.w = wpk[xA + 6];
            f16x8 ah = __builtin_bit_cast(f16x8, avh);
#pragma unroll
            for (int bb = 0; bb < 2; ++bb) {
                f16x8 bh = *(const f16x8*)(VH(bb) + xB);
                acc[gi][bb] = __builtin_amdgcn_mfma_f32_16x16x32_f16(ah, bh, acc[gi][bb], 0, 0, 0);
            }
            xA -= 32;
            xB -= 32;
        };
        for (int t = 0; t < tmax; t += 2) { step(); step(); }
    }

    const float fb = fbias[d];
#pragma unroll
    for (int gi = 0; gi < 2; ++gi) {
        const int g = gi ? (7 - wv) : wv;
        const int lb = 256 * g + 16 * row + 4 * sseg;
#pragma unroll
        for (int bb = 0; bb < 2; ++bb) {
            ushort4 vhq = *(const ushort4*)(VH(bb) + 240 + lb);
            ushort4 x0q = *(const ushort4*)(X0(bb) + lb + 4 * (lb >> 4));
            f32x4 a = acc[gi][bb];
            ushort4 o;
            o.x = f2h((a[0] + h2f(vhq.x) * fb) * h2f(x0q.x));
            o.y = f2h((a[1] + h2f(vhq.y) * fb) * h2f(x0q.y));
            o.z = f2h((a[2] + h2f(vhq.z) * fb) * h2f(x0q.z));
            o.w = f2h((a[3] + h2f(vhq.w) * fb) * h2f(x0q.w));
            *(ushort4*)&yv[((size_t)((bqa + bb) * 1024) + d) * 2048 + lb] = o;
        }
    }
#undef VH
#undef X0
}

extern "C" void kernel_launch(void* const* d_in, const int* in_sizes, int n_in,
                              void* d_out, int out_size, void* d_ws, size_t ws_size,
                              hipStream_t stream) {
    (void)in_sizes; (void)n_in; (void)out_size; (void)ws_size;
    const float* u         = (const float*)d_in[0];
    const float* in_w      = (const float*)d_in[1];
    const float* in_b      = (const float*)d_in[2];
    const float* short_w   = (const float*)d_in[3];
    const float* short_b   = (const float*)d_in[4];
    const float* mlp_w1    = (const float*)d_in[5];
    const float* mlp_b1    = (const float*)d_in[6];
    const float* mlp_w2    = (const float*)d_in[7];
    const float* mlp_b2    = (const float*)d_in[8];
    const float* mlp_w3    = (const float*)d_in[9];
    const float* mlp_b3    = (const float*)d_in[10];
    const float* mlp_wo    = (const float*)d_in[11];
    const float* freq      = (const float*)d_in[12];
    const float* filt_bias = (const float*)d_in[13];
    const float* out_w     = (const float*)d_in[14];
    const float* out_b     = (const float*)d_in[15];
    float* out = (float*)d_out;

    char* ws = (char*)d_ws;
    const size_t MB = 1024 * 1024;
    unsigned short* up_t  = (unsigned short*)ws;              // [0,48M) fp16
    unsigned short* yvh   = (unsigned short*)(ws + 48 * MB);  // [48,64M) fp16 [b][d][l]
    unsigned short* yvt   = (unsigned short*)(ws + 64 * MB);  // [64,80M) fp16 [b][l][d]
    unsigned short* w2t   = (unsigned short*)(ws + 80 * MB);  // [80,82M)
    unsigned short* kbuf  = (unsigned short*)(ws + 82 * MB);  // [82,86M) fp16
    unsigned short* uh    = (unsigned short*)(ws + 90 * MB);  // [90,106M)
    unsigned short* w1t   = (unsigned short*)(ws + 106 * MB); // [106,112M)

    hipLaunchKernelGGL(prep_kernel, dim3(6400), dim3(256), 0, stream,
                       u, uh, in_w, w1t,
                       mlp_w1, mlp_b1, mlp_w2, mlp_b2, mlp_w3, mlp_b3, mlp_wo, freq, kbuf,
                       out_w, w2t);
    hipLaunchKernelGGL((gemm8_f16_kernel<1>), dim3(24, 32), dim3(512), 0, stream,
                       uh, w1t, in_b, (void*)up_t);
    hipLaunchKernelGGL(conv_kernel, dim3(1024, 2), dim3(256), 0, stream,
                       up_t, kbuf, short_w, short_b, filt_bias, yvh);
    hipLaunchKernelGGL(post_kernel, dim3(2048), dim3(256), 0, stream,
                       yvh, yvt);
    hipLaunchKernelGGL((gemm8_f16_kernel<0>), dim3(8, 32), dim3(512), 0, stream,
                       yvt, w2t, out_b, (void*)out);
}